// Round 14
// baseline (105.390 us; speedup 1.0000x reference)
//
#include <hip/hip_runtime.h>
#include <hip/hip_bf16.h>
#include <math.h>

#define NB 8
#define NS 1024
#define NT 1024
#define NE 256
#define NHEADS 8
#define DH 32
#define LOG2E 1.4426950408889634f

typedef __attribute__((ext_vector_type(8))) short short8;
typedef __attribute__((ext_vector_type(8))) unsigned short ushort8;
typedef __attribute__((ext_vector_type(4))) float f32x4;

// ws layout (byte offsets)
#define O_VT    0u                        // ushort[8][8][32][1024] V^T swizzled
#define O_WTT   (8u<<20)                  // ushort[256*256] W_trg^T bf16 [n][k]
#define O_WTO   ((8u<<20)+131072u)        // ushort[256*256] W_out^T bf16 [n][k]
#define O_CSRC  ((8u<<20)+262144u)        // float[8*256]
#define O_CTRG  (O_CSRC+8192u)
#define O_SSRC  (O_CTRG+8192u)            // float[8192*8]
#define O_STRG  (O_SSRC+262144u)          // float[8192*8]
#define O_FLAG  (O_STRG+262144u)          // int
#define O_EST   (12u<<20)                 // float2[64][1024] {e^st', e^0.2st'}

__device__ __forceinline__ unsigned short f2bf(float f) {
    __hip_bfloat16 h = __float2bfloat16(f);
    union { __hip_bfloat16 h; unsigned short u; } c; c.h = h;
    return c.u;
}
__device__ __forceinline__ float leaky(float v) {
    return (v >= 0.f) ? v : 0.2f * v;
}
// raw v_exp_f32 (= exp2); inputs pre-scaled by LOG2E
__device__ __forceinline__ float exp2_fast(float x) {
    float r;
    asm("v_exp_f32 %0, %1" : "=v"(r) : "v"(x));
    return r;
}

// ---------------------------------------------------------------------------
// K1 setup: bid0 = mask probe; bid1/2 = c_src/c_trg; bid3..34 = W transposes.
// ---------------------------------------------------------------------------
__global__ __launch_bounds__(256) void setup_kernel(
    const unsigned* __restrict__ tmask_dw, const float* __restrict__ Wsrc,
    const float* __restrict__ Wtrg, const float* __restrict__ Wout,
    const float* __restrict__ asrc, const float* __restrict__ atrg,
    float* __restrict__ c_src, float* __restrict__ c_trg,
    unsigned short* __restrict__ Wt_t, unsigned short* __restrict__ Wt_o,
    int* __restrict__ flag) {
    __shared__ __align__(16) char sm[16640];
    const int tid = threadIdx.x;
    const int bid = blockIdx.x;

    if (bid == 0) {
        __shared__ int s_ok;
        if (tid == 0) s_ok = 1;
        __syncthreads();
        for (int i = tid; i < 2048; i += 256)
            if (tmask_dw[i] > 1u) s_ok = 0;
        __syncthreads();
        if (tid == 0) *flag = s_ok;
    } else if (bid <= 2) {
        float* a_sh = (float*)sm;
        const float* W = (bid == 1) ? Wsrc : Wtrg;
        const float* a = (bid == 1) ? asrc : atrg;
        float* c = (bid == 1) ? c_src : c_trg;
        a_sh[tid] = a[tid];
        __syncthreads();
        const int e = tid;
        float ch[8];
#pragma unroll
        for (int h = 0; h < 8; ++h) ch[h] = 0.f;
        for (int i = 0; i < 64; ++i) {
            const float4 wv = *(const float4*)&W[(size_t)e * NE + i * 4];
            const int h = i >> 3, d0 = (i & 7) * 4;
            ch[h] += wv.x * a_sh[h * 32 + d0] + wv.y * a_sh[h * 32 + d0 + 1] +
                     wv.z * a_sh[h * 32 + d0 + 2] + wv.w * a_sh[h * 32 + d0 + 3];
        }
#pragma unroll
        for (int h = 0; h < 8; ++h) c[h * NE + e] = ch[h];
    } else {
        const int q = bid - 3;
        const float* W = (q >> 4) ? Wout : Wtrg;
        unsigned short* Wt = (q >> 4) ? Wt_o : Wt_t;
        const int tl = q & 15;
        const int k0 = (tl >> 2) * 64, n0 = (tl & 3) * 64;
        float* xs = (float*)sm;                   // [64][65]
#pragma unroll
        for (int it = 0; it < 4; ++it) {
            const int slot = it * 256 + tid;
            const int k = slot >> 4, c4 = slot & 15;
            const float4 v = *(const float4*)&W[(size_t)(k0 + k) * NE + n0 + c4 * 4];
            float* p = &xs[k * 65 + c4 * 4];
            p[0] = v.x; p[1] = v.y; p[2] = v.z; p[3] = v.w;
        }
        __syncthreads();
#pragma unroll
        for (int it = 0; it < 2; ++it) {
            const int slot = it * 256 + tid;
            const int n = slot >> 3, kc = slot & 7;
            ushort8 v;
#pragma unroll
            for (int e = 0; e < 8; ++e)
                v[e] = f2bf(xs[(kc * 8 + e) * 65 + n]);
            *(ushort8*)&Wt[(size_t)(n0 + n) * NE + k0 + kc * 8] = v;
        }
    }
}

// ---------------------------------------------------------------------------
// K2 mid: bid<256 -> V gemm (trg @ W_trg, bf16 MFMA) -> Vt swizzled;
// bid>=256 -> score rows; trg-half additionally writes est tables
// est[bh][t] = {e^{st'}, e^{0.2 st'}} (0 if masked).
// ---------------------------------------------------------------------------
__global__ __launch_bounds__(256) void mid_kernel(
    const float* __restrict__ src, const float* __restrict__ trg,
    const float* __restrict__ c_src, const float* __restrict__ c_trg,
    const unsigned short* __restrict__ Wt_t, unsigned short* __restrict__ Vt,
    float* __restrict__ ssrc, float* __restrict__ strg,
    const void* __restrict__ tmask, const int* __restrict__ flag_p,
    float2* __restrict__ estg) {
    __shared__ __align__(16) char sm[49152];
    const int tid = threadIdx.x;
    const int bid = blockIdx.x;

    if (bid < 256) {
        unsigned short* As = (unsigned short*)sm;             // [64][256]
        unsigned short* ldsT = (unsigned short*)(sm + 32768); // [128][64]
        const int lane = tid & 63, w = tid >> 6;
        const int row0 = (bid >> 1) * 64;
        const int col0 = (bid & 1) * 128;

#pragma unroll
        for (int it = 0; it < 8; ++it) {
            const int gf = it * 256 + tid;
            const int row = gf >> 5, g3 = gf & 31;
            const float4 a = *(const float4*)&trg[(size_t)(row0 + row) * NE + g3 * 8];
            const float4 b = *(const float4*)&trg[(size_t)(row0 + row) * NE + g3 * 8 + 4];
            ushort8 v;
            v[0] = f2bf(a.x); v[1] = f2bf(a.y); v[2] = f2bf(a.z); v[3] = f2bf(a.w);
            v[4] = f2bf(b.x); v[5] = f2bf(b.y); v[6] = f2bf(b.z); v[7] = f2bf(b.w);
            *(ushort8*)&As[row * NE + ((g3 ^ (row & 7)) * 8)] = v;
        }
        __syncthreads();

        const int r = lane & 15, g = lane >> 4;
        short8 af[8];
#pragma unroll
        for (int kk = 0; kk < 8; ++kk)
            af[kk] = *(const short8*)&As[(w * 16 + r) * NE + (((kk * 4 + g) ^ (r & 7)) * 8)];

        f32x4 acc[8];
#pragma unroll
        for (int nt = 0; nt < 8; ++nt) acc[nt] = (f32x4){0.f, 0.f, 0.f, 0.f};
#pragma unroll
        for (int kk = 0; kk < 8; ++kk) {
#pragma unroll
            for (int nt = 0; nt < 8; ++nt) {
                const int col = col0 + nt * 16 + r;
                const short8 bf = *(const short8*)&Wt_t[(size_t)col * NE + kk * 32 + g * 8];
                acc[nt] = __builtin_amdgcn_mfma_f32_16x16x32_bf16(af[kk], bf, acc[nt], 0, 0, 0);
            }
        }
        __syncthreads();

        // transpose epilogue: ldsT[col][t ^ ((col&7)<<3)] = bf16(acc)
#pragma unroll
        for (int nt = 0; nt < 8; ++nt) {
            const int cl = nt * 16 + r;
            const int sw = (cl & 7) << 3;
#pragma unroll
            for (int j = 0; j < 4; ++j) {
                const int t = w * 16 + g * 4 + j;
                ldsT[cl * 64 + (t ^ sw)] = f2bf(acc[nt][j]);
            }
        }
        __syncthreads();

        const int b = row0 >> 10, t0 = row0 & 1023;
#pragma unroll
        for (int it = 0; it < 4; ++it) {
            const int slot = it * 256 + tid;
            const int cl = slot >> 3, ch = slot & 7;
            const int colg = col0 + cl;
            const int h = colg >> 5, d = colg & 31;
            *(ushort8*)&Vt[(((size_t)(b * 8 + h)) * 32 + d) * 1024 + t0 + ch * 8] =
                *(const ushort8*)&ldsT[cl * 64 + ch * 8];
        }
    } else {
        float* xs = (float*)sm;                  // [32][256]
        float* cs = (float*)(sm + 32768);        // [8][256]
        const int rowg0 = (bid - 256) * 32;
        const bool is_src = rowg0 < NB * NS;
        const float* X = is_src ? (src + (size_t)rowg0 * NE)
                                : (trg + (size_t)(rowg0 - NB * NS) * NE);
        const float* C = is_src ? c_src : c_trg;
        float* S = is_src ? (ssrc + (size_t)rowg0 * NHEADS)
                          : (strg + (size_t)(rowg0 - NB * NS) * NHEADS);

#pragma unroll
        for (int it = 0; it < 8; ++it) {
            const int slot = it * 256 + tid;
            const int row = slot >> 6, c4 = slot & 63;
            *(float4*)&xs[row * NE + c4 * 4] =
                *(const float4*)&X[(size_t)row * NE + c4 * 4];
            cs[slot] = C[slot];
        }
        __syncthreads();

        const int r = tid >> 3, h = tid & 7;
        float s = 0.f;
        for (int e = 0; e < NE; e += 4) {
            const float4 x = *(const float4*)&xs[r * NE + e];
            const float4 c = *(const float4*)&cs[h * NE + e];
            s += x.x * c.x + x.y * c.y + x.z * c.z + x.w * c.w;
        }
        S[(size_t)r * NHEADS + h] = s;

        if (!is_src) {
            const int rowg = rowg0 - NB * NS + r;        // b*1024 + t
            const int flag = *flag_p;
            const bool mv = flag ? (((const int*)tmask)[rowg] != 0)
                                 : (((const unsigned char*)tmask)[rowg] != 0);
            const int bb = rowg >> 10, tt = rowg & 1023;
            const float s2 = s * LOG2E;
            float2 e;
            e.x = mv ? exp2_fast(s2) : 0.f;
            e.y = mv ? exp2_fast(0.2f * s2) : 0.f;
            estg[(size_t)(bb * 8 + h) * 1024 + tt] = e;
        }
    }
}

// ---------------------------------------------------------------------------
// K3 combo: 1024 blocks x 512 threads, two families interleaved by bid&1.
// Identity used by both: exp2(leaky(ss+st)) == max(est1*E1, est2*E2) where
// est = {e^{st'}, e^{0.2st'}} (precomputed, masked->0), E1=e^{ss'}, E2=e^{0.2ss'}
// (leaky(x) = max(x, 0.2x), exp2 monotone). 2 mul + 1 max per element, no
// transcendentals in the hot loops (2 exp2 per lane total).
// even bid -> aggout: est from L2/L1 (8KB/bh, 16-fold lane broadcast),
//   unnormalized MFMA vs Vt + row sums -> agg -> LDS -> out-GEMM.
//   LDS only 8.7 KB (agg_sw + s_inv) — no s_sm staging.
// odd bid  -> attn: est in 32 VGPRs, sums + 1KB contiguous stores. No LDS.
// ---------------------------------------------------------------------------
__global__ __launch_bounds__(512) void combo_kernel(
    const float* __restrict__ ssrc, const float* __restrict__ strg,
    const void* __restrict__ smask, const void* __restrict__ tmask,
    const int* __restrict__ flag_p, const unsigned short* __restrict__ Vt,
    const unsigned short* __restrict__ Wt_o, const float2* __restrict__ estg,
    float* __restrict__ attn, float* __restrict__ out) {
    __shared__ __align__(16) unsigned short agg_sw[16 * 256];  // 8 KB
    __shared__ float s_inv[128];
    const int bid = blockIdx.x;
    const int tid = threadIdx.x;
    const int lane = tid & 63;
    const int w = tid >> 6;
    const int flag = *flag_p;

    if ((bid & 1) == 0) {
        // ---------------- aggout branch ----------------
        const int idx = bid >> 1;
        const int q = idx & 63;
        const int b = idx >> 6;

        const int r = lane & 15;
        const int g = lane >> 4;
        const int srow = q * 16 + r;
        const bool rowv = flag ? (((const int*)smask)[b * NS + srow] != 0)
                               : (((const unsigned char*)smask)[b * NS + srow] != 0);
        const int sw = (r & 7) << 3;
        const int h = w;
        const float ss2 = ssrc[((size_t)b * NS + srow) * NHEADS + h] * LOG2E;
        const float E1 = exp2_fast(ss2);
        const float E2 = exp2_fast(0.2f * ss2);
        const unsigned short* vr0 = Vt + (size_t)(b * 8 + h) * 32768 + r * 1024;
        const unsigned short* vr1 = vr0 + 16 * 1024;
        const float2* eb = estg + (size_t)(b * 8 + h) * 1024;

        f32x4 acc0 = {0.f, 0.f, 0.f, 0.f};
        f32x4 acc1 = {0.f, 0.f, 0.f, 0.f};
        float sum = 0.f;
#pragma unroll 4
        for (int c = 0; c < 32; ++c) {
            const int tb = c * 32 + g * 8;
            const short8 b0 = *(const short8*)&vr0[tb ^ sw];
            const short8 b1 = *(const short8*)&vr1[tb ^ sw];
            const float4 q0 = *(const float4*)&eb[tb];
            const float4 q1 = *(const float4*)&eb[tb + 2];
            const float4 q2 = *(const float4*)&eb[tb + 4];
            const float4 q3 = *(const float4*)&eb[tb + 6];
            float p[8];
            p[0] = fmaxf(q0.x * E1, q0.y * E2);
            p[1] = fmaxf(q0.z * E1, q0.w * E2);
            p[2] = fmaxf(q1.x * E1, q1.y * E2);
            p[3] = fmaxf(q1.z * E1, q1.w * E2);
            p[4] = fmaxf(q2.x * E1, q2.y * E2);
            p[5] = fmaxf(q2.z * E1, q2.w * E2);
            p[6] = fmaxf(q3.x * E1, q3.y * E2);
            p[7] = fmaxf(q3.z * E1, q3.w * E2);
            short8 pa;
#pragma unroll
            for (int e = 0; e < 8; ++e) {
                sum += p[e];
                pa[e] = (short)f2bf(p[e]);
            }
            acc0 = __builtin_amdgcn_mfma_f32_16x16x32_bf16(pa, b0, acc0, 0, 0, 0);
            acc1 = __builtin_amdgcn_mfma_f32_16x16x32_bf16(pa, b1, acc1, 0, 0, 0);
        }
        sum += __shfl_xor(sum, 16);
        sum += __shfl_xor(sum, 32);
        const float inv = (rowv && sum > 0.f) ? 1.f / sum : 0.f;
        if (g == 0) s_inv[h * 16 + r] = inv;
        __syncthreads();

#pragma unroll
        for (int j = 0; j < 4; ++j) {
            const int row = g * 4 + j;
            const float iv = s_inv[h * 16 + row];
            int col = h * 32 + r;
            agg_sw[row * 256 + ((((col >> 3) ^ (row & 7)) << 3) | (col & 7))] =
                f2bf(acc0[j] * iv);
            col += 16;
            agg_sw[row * 256 + ((((col >> 3) ^ (row & 7)) << 3) | (col & 7))] =
                f2bf(acc1[j] * iv);
        }
        __syncthreads();

        f32x4 oacc[2];
#pragma unroll
        for (int nt = 0; nt < 2; ++nt) oacc[nt] = (f32x4){0.f, 0.f, 0.f, 0.f};
#pragma unroll
        for (int kk = 0; kk < 8; ++kk) {
            const short8 af = *(const short8*)&agg_sw[r * 256 + (((kk * 4 + g) ^ (r & 7)) * 8)];
#pragma unroll
            for (int nt = 0; nt < 2; ++nt) {
                const int col = w * 32 + nt * 16 + r;
                const short8 bf = *(const short8*)&Wt_o[(size_t)col * NE + kk * 32 + g * 8];
                oacc[nt] = __builtin_amdgcn_mfma_f32_16x16x32_bf16(af, bf, oacc[nt], 0, 0, 0);
            }
        }
#pragma unroll
        for (int nt = 0; nt < 2; ++nt) {
            const int col = w * 32 + nt * 16 + r;
#pragma unroll
            for (int j = 0; j < 4; ++j)
                out[((size_t)b * NS + q * 16 + g * 4 + j) * NE + col] = oacc[nt][j];
        }
    } else {
        // ---------------- attn branch (exp-free streaming) ----------------
        const int idx = bid >> 1;
        const int b = idx >> 6;
        const int h = (idx >> 3) & 7;
        const int hq = idx & 7;

        // hoist est pairs for this lane's 16 t's into regs
        float2 e[16];
        const float2* eb = estg + (size_t)(b * 8 + h) * 1024;
#pragma unroll
        for (int qq = 0; qq < 4; ++qq) {
            const float4 p0 = *(const float4*)&eb[qq * 256 + lane * 4];
            const float4 p1 = *(const float4*)&eb[qq * 256 + lane * 4 + 2];
            e[qq * 4 + 0] = make_float2(p0.x, p0.y);
            e[qq * 4 + 1] = make_float2(p0.z, p0.w);
            e[qq * 4 + 2] = make_float2(p1.x, p1.y);
            e[qq * 4 + 3] = make_float2(p1.z, p1.w);
        }

        const int row0 = hq * 128 + w * 16;
        for (int rr = 0; rr < 16; ++rr) {
            const int srow = row0 + rr;
            const float ss2 = ssrc[((size_t)b * NS + srow) * NHEADS + h] * LOG2E;
            const bool rowv = flag ? (((const int*)smask)[b * NS + srow] != 0)
                                   : (((const unsigned char*)smask)[b * NS + srow] != 0);
            const float E1 = exp2_fast(ss2);
            const float E2 = exp2_fast(0.2f * ss2);

            float sum = 0.f;
#pragma unroll
            for (int k = 0; k < 16; ++k)
                sum += fmaxf(e[k].x * E1, e[k].y * E2);
#pragma unroll
            for (int off = 32; off >= 1; off >>= 1)
                sum += __shfl_xor(sum, off);
            const float inv = (rowv && sum > 0.f) ? 1.f / sum : 0.f;
            const float v1 = E1 * inv, v2 = E2 * inv;

            float* arow = attn + ((size_t)(b * NHEADS + h) * NS + srow) * NT;
#pragma unroll
            for (int qq = 0; qq < 4; ++qq) {
                float4 o;
                o.x = fmaxf(e[qq * 4 + 0].x * v1, e[qq * 4 + 0].y * v2);
                o.y = fmaxf(e[qq * 4 + 1].x * v1, e[qq * 4 + 1].y * v2);
                o.z = fmaxf(e[qq * 4 + 2].x * v1, e[qq * 4 + 2].y * v2);
                o.w = fmaxf(e[qq * 4 + 3].x * v1, e[qq * 4 + 3].y * v2);
                *(float4*)&arow[qq * 256 + lane * 4] = o;
            }
        }
    }
}

extern "C" void kernel_launch(void* const* d_in, const int* in_sizes, int n_in,
                              void* d_out, int out_size, void* d_ws, size_t ws_size,
                              hipStream_t stream) {
    const float* src   = (const float*)d_in[0];
    const float* trg   = (const float*)d_in[1];
    const void*  smask = d_in[2];
    const void*  tmask = d_in[3];
    const float* Wsrc  = (const float*)d_in[4];
    const float* Wtrg  = (const float*)d_in[5];
    const float* asrc  = (const float*)d_in[6];
    const float* atrg  = (const float*)d_in[7];
    const float* Wout  = (const float*)d_in[8];

    float* out  = (float*)d_out;
    float* attn = out + (size_t)NB * NS * NE;

    char* wsb = (char*)d_ws;
    unsigned short* Vt   = (unsigned short*)(wsb + O_VT);
    unsigned short* Wt_t = (unsigned short*)(wsb + O_WTT);
    unsigned short* Wt_o = (unsigned short*)(wsb + O_WTO);
    float* c_src = (float*)(wsb + O_CSRC);
    float* c_trg = (float*)(wsb + O_CTRG);
    float* ssrc  = (float*)(wsb + O_SSRC);
    float* strg  = (float*)(wsb + O_STRG);
    int*   flag  = (int*)(wsb + O_FLAG);
    float2* estg = (float2*)(wsb + O_EST);

    setup_kernel<<<35, 256, 0, stream>>>(
        (const unsigned*)tmask, Wsrc, Wtrg, Wout, asrc, atrg,
        c_src, c_trg, Wt_t, Wt_o, flag);

    mid_kernel<<<768, 256, 0, stream>>>(
        src, trg, c_src, c_trg, Wt_t, Vt, ssrc, strg, tmask, flag, estg);

    combo_kernel<<<1024, 512, 0, stream>>>(
        ssrc, strg, smask, tmask, flag, Vt, Wt_o, estg, attn, out);
}

// Round 15
// 93.383 us; speedup vs baseline: 1.1286x; 1.1286x over previous
//
#include <hip/hip_runtime.h>
#include <hip/hip_bf16.h>
#include <math.h>

#define NB 8
#define NS 1024
#define NT 1024
#define NE 256
#define NHEADS 8
#define DH 32
#define LOG2E 1.4426950408889634f

typedef __attribute__((ext_vector_type(8))) short short8;
typedef __attribute__((ext_vector_type(8))) unsigned short ushort8;
typedef __attribute__((ext_vector_type(4))) float f32x4;

// ws layout (byte offsets)
#define O_VT    0u                        // ushort[8][8][32][1024] V^T swizzled
#define O_WTT   (8u<<20)                  // ushort[256*256] W_trg^T bf16 [n][k]
#define O_WTO   ((8u<<20)+131072u)        // ushort[256*256] W_out^T bf16 [n][k]
#define O_CSRC  ((8u<<20)+262144u)        // float[8*256]
#define O_CTRG  (O_CSRC+8192u)
#define O_SSRC  (O_CTRG+8192u)            // float[8192*8]
#define O_STRG  (O_SSRC+262144u)          // float[8192*8]
#define O_FLAG  (O_STRG+262144u)          // int
#define O_EST   (12u<<20)                 // float2[64][1024] {e^st', e^0.2st'}

__device__ __forceinline__ unsigned short f2bf(float f) {
    __hip_bfloat16 h = __float2bfloat16(f);
    union { __hip_bfloat16 h; unsigned short u; } c; c.h = h;
    return c.u;
}
__device__ __forceinline__ float leaky(float v) {
    return (v >= 0.f) ? v : 0.2f * v;
}
// raw v_exp_f32 (= exp2); inputs pre-scaled by LOG2E
__device__ __forceinline__ float exp2_fast(float x) {
    float r;
    asm("v_exp_f32 %0, %1" : "=v"(r) : "v"(x));
    return r;
}

// ---------------------------------------------------------------------------
// K1 setup: bid0 = mask probe; bid1/2 = c_src/c_trg; bid3..34 = W transposes.
// ---------------------------------------------------------------------------
__global__ __launch_bounds__(256) void setup_kernel(
    const unsigned* __restrict__ tmask_dw, const float* __restrict__ Wsrc,
    const float* __restrict__ Wtrg, const float* __restrict__ Wout,
    const float* __restrict__ asrc, const float* __restrict__ atrg,
    float* __restrict__ c_src, float* __restrict__ c_trg,
    unsigned short* __restrict__ Wt_t, unsigned short* __restrict__ Wt_o,
    int* __restrict__ flag) {
    __shared__ __align__(16) char sm[16640];
    const int tid = threadIdx.x;
    const int bid = blockIdx.x;

    if (bid == 0) {
        __shared__ int s_ok;
        if (tid == 0) s_ok = 1;
        __syncthreads();
        for (int i = tid; i < 2048; i += 256)
            if (tmask_dw[i] > 1u) s_ok = 0;
        __syncthreads();
        if (tid == 0) *flag = s_ok;
    } else if (bid <= 2) {
        float* a_sh = (float*)sm;
        const float* W = (bid == 1) ? Wsrc : Wtrg;
        const float* a = (bid == 1) ? asrc : atrg;
        float* c = (bid == 1) ? c_src : c_trg;
        a_sh[tid] = a[tid];
        __syncthreads();
        const int e = tid;
        float ch[8];
#pragma unroll
        for (int h = 0; h < 8; ++h) ch[h] = 0.f;
        for (int i = 0; i < 64; ++i) {
            const float4 wv = *(const float4*)&W[(size_t)e * NE + i * 4];
            const int h = i >> 3, d0 = (i & 7) * 4;
            ch[h] += wv.x * a_sh[h * 32 + d0] + wv.y * a_sh[h * 32 + d0 + 1] +
                     wv.z * a_sh[h * 32 + d0 + 2] + wv.w * a_sh[h * 32 + d0 + 3];
        }
#pragma unroll
        for (int h = 0; h < 8; ++h) c[h * NE + e] = ch[h];
    } else {
        const int q = bid - 3;
        const float* W = (q >> 4) ? Wout : Wtrg;
        unsigned short* Wt = (q >> 4) ? Wt_o : Wt_t;
        const int tl = q & 15;
        const int k0 = (tl >> 2) * 64, n0 = (tl & 3) * 64;
        float* xs = (float*)sm;                   // [64][65]
#pragma unroll
        for (int it = 0; it < 4; ++it) {
            const int slot = it * 256 + tid;
            const int k = slot >> 4, c4 = slot & 15;
            const float4 v = *(const float4*)&W[(size_t)(k0 + k) * NE + n0 + c4 * 4];
            float* p = &xs[k * 65 + c4 * 4];
            p[0] = v.x; p[1] = v.y; p[2] = v.z; p[3] = v.w;
        }
        __syncthreads();
#pragma unroll
        for (int it = 0; it < 2; ++it) {
            const int slot = it * 256 + tid;
            const int n = slot >> 3, kc = slot & 7;
            ushort8 v;
#pragma unroll
            for (int e = 0; e < 8; ++e)
                v[e] = f2bf(xs[(kc * 8 + e) * 65 + n]);
            *(ushort8*)&Wt[(size_t)(n0 + n) * NE + k0 + kc * 8] = v;
        }
    }
}

// ---------------------------------------------------------------------------
// K2 mid: bid<256 -> V gemm (trg @ W_trg, bf16 MFMA) -> Vt swizzled;
// bid>=256 -> score rows; trg-half additionally writes est tables
// est[bh][t] = {e^{st'}, e^{0.2 st'}} (0 if masked).
// ---------------------------------------------------------------------------
__global__ __launch_bounds__(256) void mid_kernel(
    const float* __restrict__ src, const float* __restrict__ trg,
    const float* __restrict__ c_src, const float* __restrict__ c_trg,
    const unsigned short* __restrict__ Wt_t, unsigned short* __restrict__ Vt,
    float* __restrict__ ssrc, float* __restrict__ strg,
    const void* __restrict__ tmask, const int* __restrict__ flag_p,
    float2* __restrict__ estg) {
    __shared__ __align__(16) char sm[49152];
    const int tid = threadIdx.x;
    const int bid = blockIdx.x;

    if (bid < 256) {
        unsigned short* As = (unsigned short*)sm;             // [64][256]
        unsigned short* ldsT = (unsigned short*)(sm + 32768); // [128][64]
        const int lane = tid & 63, w = tid >> 6;
        const int row0 = (bid >> 1) * 64;
        const int col0 = (bid & 1) * 128;

#pragma unroll
        for (int it = 0; it < 8; ++it) {
            const int gf = it * 256 + tid;
            const int row = gf >> 5, g3 = gf & 31;
            const float4 a = *(const float4*)&trg[(size_t)(row0 + row) * NE + g3 * 8];
            const float4 b = *(const float4*)&trg[(size_t)(row0 + row) * NE + g3 * 8 + 4];
            ushort8 v;
            v[0] = f2bf(a.x); v[1] = f2bf(a.y); v[2] = f2bf(a.z); v[3] = f2bf(a.w);
            v[4] = f2bf(b.x); v[5] = f2bf(b.y); v[6] = f2bf(b.z); v[7] = f2bf(b.w);
            *(ushort8*)&As[row * NE + ((g3 ^ (row & 7)) * 8)] = v;
        }
        __syncthreads();

        const int r = lane & 15, g = lane >> 4;
        short8 af[8];
#pragma unroll
        for (int kk = 0; kk < 8; ++kk)
            af[kk] = *(const short8*)&As[(w * 16 + r) * NE + (((kk * 4 + g) ^ (r & 7)) * 8)];

        f32x4 acc[8];
#pragma unroll
        for (int nt = 0; nt < 8; ++nt) acc[nt] = (f32x4){0.f, 0.f, 0.f, 0.f};
#pragma unroll
        for (int kk = 0; kk < 8; ++kk) {
#pragma unroll
            for (int nt = 0; nt < 8; ++nt) {
                const int col = col0 + nt * 16 + r;
                const short8 bf = *(const short8*)&Wt_t[(size_t)col * NE + kk * 32 + g * 8];
                acc[nt] = __builtin_amdgcn_mfma_f32_16x16x32_bf16(af[kk], bf, acc[nt], 0, 0, 0);
            }
        }
        __syncthreads();

        // transpose epilogue: ldsT[col][t ^ ((col&7)<<3)] = bf16(acc)
#pragma unroll
        for (int nt = 0; nt < 8; ++nt) {
            const int cl = nt * 16 + r;
            const int sw = (cl & 7) << 3;
#pragma unroll
            for (int j = 0; j < 4; ++j) {
                const int t = w * 16 + g * 4 + j;
                ldsT[cl * 64 + (t ^ sw)] = f2bf(acc[nt][j]);
            }
        }
        __syncthreads();

        const int b = row0 >> 10, t0 = row0 & 1023;
#pragma unroll
        for (int it = 0; it < 4; ++it) {
            const int slot = it * 256 + tid;
            const int cl = slot >> 3, ch = slot & 7;
            const int colg = col0 + cl;
            const int h = colg >> 5, d = colg & 31;
            *(ushort8*)&Vt[(((size_t)(b * 8 + h)) * 32 + d) * 1024 + t0 + ch * 8] =
                *(const ushort8*)&ldsT[cl * 64 + ch * 8];
        }
    } else {
        float* xs = (float*)sm;                  // [32][256]
        float* cs = (float*)(sm + 32768);        // [8][256]
        const int rowg0 = (bid - 256) * 32;
        const bool is_src = rowg0 < NB * NS;
        const float* X = is_src ? (src + (size_t)rowg0 * NE)
                                : (trg + (size_t)(rowg0 - NB * NS) * NE);
        const float* C = is_src ? c_src : c_trg;
        float* S = is_src ? (ssrc + (size_t)rowg0 * NHEADS)
                          : (strg + (size_t)(rowg0 - NB * NS) * NHEADS);

#pragma unroll
        for (int it = 0; it < 8; ++it) {
            const int slot = it * 256 + tid;
            const int row = slot >> 6, c4 = slot & 63;
            *(float4*)&xs[row * NE + c4 * 4] =
                *(const float4*)&X[(size_t)row * NE + c4 * 4];
            cs[slot] = C[slot];
        }
        __syncthreads();

        const int r = tid >> 3, h = tid & 7;
        float s = 0.f;
        for (int e = 0; e < NE; e += 4) {
            const float4 x = *(const float4*)&xs[r * NE + e];
            const float4 c = *(const float4*)&cs[h * NE + e];
            s += x.x * c.x + x.y * c.y + x.z * c.z + x.w * c.w;
        }
        S[(size_t)r * NHEADS + h] = s;

        if (!is_src) {
            const int rowg = rowg0 - NB * NS + r;        // b*1024 + t
            const int flag = *flag_p;
            const bool mv = flag ? (((const int*)tmask)[rowg] != 0)
                                 : (((const unsigned char*)tmask)[rowg] != 0);
            const int bb = rowg >> 10, tt = rowg & 1023;
            const float s2 = s * LOG2E;
            float2 e;
            e.x = mv ? exp2_fast(s2) : 0.f;
            e.y = mv ? exp2_fast(0.2f * s2) : 0.f;
            estg[(size_t)(bb * 8 + h) * 1024 + tt] = e;
        }
    }
}

// ---------------------------------------------------------------------------
// K3 combo (R13 structure): 1024 blocks x 512 threads, two families.
// Family selector = (bid>>3)&1 — with round-robin bid%8 -> XCD mapping this
// alternates families WITHIN each XCD (R13's bid&1 segregated whole XCDs:
// all-even bids landed on XCDs 0/2/4/6). idx = (bid&7)|((bid>>4)<<3).
// aggout family: s_sm LDS staging + exp2(leaky)->bf16 unnormalized MFMA vs Vt
//   + row sums -> agg -> LDS -> out-GEMM  (R13's verified branch, unchanged).
// attn family: exp-free streaming from est tables (R13's verified branch).
// ---------------------------------------------------------------------------
__global__ __launch_bounds__(512) void combo_kernel(
    const float* __restrict__ ssrc, const float* __restrict__ strg,
    const void* __restrict__ smask, const void* __restrict__ tmask,
    const int* __restrict__ flag_p, const unsigned short* __restrict__ Vt,
    const unsigned short* __restrict__ Wt_o, const float2* __restrict__ estg,
    float* __restrict__ attn, float* __restrict__ out) {
    __shared__ __align__(16) char sm[41472];
    const int bid = blockIdx.x;
    const int tid = threadIdx.x;
    const int lane = tid & 63;
    const int w = tid >> 6;
    const int flag = *flag_p;

    const int fam = (bid >> 3) & 1;
    const int idx = (bid & 7) | ((bid >> 4) << 3);   // bijective [0,512)

    if (fam == 0) {
        // ---------------- aggout branch ----------------
        const int q = idx & 63;
        const int b = idx >> 6;
        float* s_sm = (float*)sm;                                 // [8][1024]
        unsigned short* agg_sw = (unsigned short*)(sm + 32768);   // [16*256]
        float* s_inv = (float*)(sm + 32768 + 8192);               // [8][16]

        for (int t = tid; t < NT; t += 512) {
            const bool mv = flag ? (((const int*)tmask)[b * NT + t] != 0)
                                 : (((const unsigned char*)tmask)[b * NT + t] != 0);
            const float4 s0 = *(const float4*)&strg[((size_t)b * NT + t) * 8];
            const float4 s1 = *(const float4*)&strg[((size_t)b * NT + t) * 8 + 4];
            const float sv[8] = {s0.x, s0.y, s0.z, s0.w, s1.x, s1.y, s1.z, s1.w};
#pragma unroll
            for (int h = 0; h < 8; ++h)
                s_sm[h * 1024 + t] = mv ? sv[h] * LOG2E : -1e30f;
        }
        __syncthreads();

        const int r = lane & 15;
        const int g = lane >> 4;
        const int srow = q * 16 + r;
        const bool rowv = flag ? (((const int*)smask)[b * NS + srow] != 0)
                               : (((const unsigned char*)smask)[b * NS + srow] != 0);
        const int sw = (r & 7) << 3;
        const int h = w;
        const float ss2 = ssrc[((size_t)b * NS + srow) * NHEADS + h] * LOG2E;
        const unsigned short* vr0 = Vt + (size_t)(b * 8 + h) * 32768 + r * 1024;
        const unsigned short* vr1 = vr0 + 16 * 1024;

        f32x4 acc0 = {0.f, 0.f, 0.f, 0.f};
        f32x4 acc1 = {0.f, 0.f, 0.f, 0.f};
        float sum = 0.f;
#pragma unroll 4
        for (int c = 0; c < 32; ++c) {
            const int tb = c * 32 + g * 8;
            const short8 b0 = *(const short8*)&vr0[tb ^ sw];
            const short8 b1 = *(const short8*)&vr1[tb ^ sw];
            const float4 v0 = *(const float4*)&s_sm[h * 1024 + tb];
            const float4 v1 = *(const float4*)&s_sm[h * 1024 + tb + 4];
            const float vv[8] = {v0.x, v0.y, v0.z, v0.w, v1.x, v1.y, v1.z, v1.w};
            short8 pa;
#pragma unroll
            for (int e = 0; e < 8; ++e) {
                const float p = exp2_fast(leaky(ss2 + vv[e]));
                sum += p;
                pa[e] = (short)f2bf(p);
            }
            acc0 = __builtin_amdgcn_mfma_f32_16x16x32_bf16(pa, b0, acc0, 0, 0, 0);
            acc1 = __builtin_amdgcn_mfma_f32_16x16x32_bf16(pa, b1, acc1, 0, 0, 0);
        }
        sum += __shfl_xor(sum, 16);
        sum += __shfl_xor(sum, 32);
        const float inv = (rowv && sum > 0.f) ? 1.f / sum : 0.f;
        if (g == 0) s_inv[h * 16 + r] = inv;
        __syncthreads();

#pragma unroll
        for (int j = 0; j < 4; ++j) {
            const int row = g * 4 + j;
            const float iv = s_inv[h * 16 + row];
            int col = h * 32 + r;
            agg_sw[row * 256 + ((((col >> 3) ^ (row & 7)) << 3) | (col & 7))] =
                f2bf(acc0[j] * iv);
            col += 16;
            agg_sw[row * 256 + ((((col >> 3) ^ (row & 7)) << 3) | (col & 7))] =
                f2bf(acc1[j] * iv);
        }
        __syncthreads();

        f32x4 oacc[2];
#pragma unroll
        for (int nt = 0; nt < 2; ++nt) oacc[nt] = (f32x4){0.f, 0.f, 0.f, 0.f};
#pragma unroll
        for (int kk = 0; kk < 8; ++kk) {
            const short8 af = *(const short8*)&agg_sw[r * 256 + (((kk * 4 + g) ^ (r & 7)) * 8)];
#pragma unroll
            for (int nt = 0; nt < 2; ++nt) {
                const int col = w * 32 + nt * 16 + r;
                const short8 bf = *(const short8*)&Wt_o[(size_t)col * NE + kk * 32 + g * 8];
                oacc[nt] = __builtin_amdgcn_mfma_f32_16x16x32_bf16(af, bf, oacc[nt], 0, 0, 0);
            }
        }
#pragma unroll
        for (int nt = 0; nt < 2; ++nt) {
            const int col = w * 32 + nt * 16 + r;
#pragma unroll
            for (int j = 0; j < 4; ++j)
                out[((size_t)b * NS + q * 16 + g * 4 + j) * NE + col] = oacc[nt][j];
        }
    } else {
        // ---------------- attn branch (exp-free streaming) ----------------
        const int b = idx >> 6;
        const int h = (idx >> 3) & 7;
        const int hq = idx & 7;

        // hoist est pairs for this lane's 16 t's into regs
        float2 e[16];
        const float2* eb = estg + (size_t)(b * 8 + h) * 1024;
#pragma unroll
        for (int qq = 0; qq < 4; ++qq) {
            const float4 p0 = *(const float4*)&eb[qq * 256 + lane * 4];
            const float4 p1 = *(const float4*)&eb[qq * 256 + lane * 4 + 2];
            e[qq * 4 + 0] = make_float2(p0.x, p0.y);
            e[qq * 4 + 1] = make_float2(p0.z, p0.w);
            e[qq * 4 + 2] = make_float2(p1.x, p1.y);
            e[qq * 4 + 3] = make_float2(p1.z, p1.w);
        }

        const int row0 = hq * 128 + w * 16;
        for (int rr = 0; rr < 16; ++rr) {
            const int srow = row0 + rr;
            const float ss2 = ssrc[((size_t)b * NS + srow) * NHEADS + h] * LOG2E;
            const bool rowv = flag ? (((const int*)smask)[b * NS + srow] != 0)
                                   : (((const unsigned char*)smask)[b * NS + srow] != 0);
            const float e1 = exp2_fast(ss2);
            const float e2 = exp2_fast(0.2f * ss2);
            const float thr = exp2_fast(-ss2);

            float sum = 0.f;
#pragma unroll
            for (int k = 0; k < 16; ++k)
                sum += (e[k].x >= thr) ? e[k].x * e1 : e[k].y * e2;
#pragma unroll
            for (int off = 32; off >= 1; off >>= 1)
                sum += __shfl_xor(sum, off);
            const float inv = (rowv && sum > 0.f) ? 1.f / sum : 0.f;
            const float v1 = e1 * inv, v2 = e2 * inv;

            float* arow = attn + ((size_t)(b * NHEADS + h) * NS + srow) * NT;
#pragma unroll
            for (int qq = 0; qq < 4; ++qq) {
                float4 o;
                o.x = (e[qq * 4 + 0].x >= thr) ? e[qq * 4 + 0].x * v1 : e[qq * 4 + 0].y * v2;
                o.y = (e[qq * 4 + 1].x >= thr) ? e[qq * 4 + 1].x * v1 : e[qq * 4 + 1].y * v2;
                o.z = (e[qq * 4 + 2].x >= thr) ? e[qq * 4 + 2].x * v1 : e[qq * 4 + 2].y * v2;
                o.w = (e[qq * 4 + 3].x >= thr) ? e[qq * 4 + 3].x * v1 : e[qq * 4 + 3].y * v2;
                *(float4*)&arow[qq * 256 + lane * 4] = o;
            }
        }
    }
}

extern "C" void kernel_launch(void* const* d_in, const int* in_sizes, int n_in,
                              void* d_out, int out_size, void* d_ws, size_t ws_size,
                              hipStream_t stream) {
    const float* src   = (const float*)d_in[0];
    const float* trg   = (const float*)d_in[1];
    const void*  smask = d_in[2];
    const void*  tmask = d_in[3];
    const float* Wsrc  = (const float*)d_in[4];
    const float* Wtrg  = (const float*)d_in[5];
    const float* asrc  = (const float*)d_in[6];
    const float* atrg  = (const float*)d_in[7];
    const float* Wout  = (const float*)d_in[8];

    float* out  = (float*)d_out;
    float* attn = out + (size_t)NB * NS * NE;

    char* wsb = (char*)d_ws;
    unsigned short* Vt   = (unsigned short*)(wsb + O_VT);
    unsigned short* Wt_t = (unsigned short*)(wsb + O_WTT);
    unsigned short* Wt_o = (unsigned short*)(wsb + O_WTO);
    float* c_src = (float*)(wsb + O_CSRC);
    float* c_trg = (float*)(wsb + O_CTRG);
    float* ssrc  = (float*)(wsb + O_SSRC);
    float* strg  = (float*)(wsb + O_STRG);
    int*   flag  = (int*)(wsb + O_FLAG);
    float2* estg = (float2*)(wsb + O_EST);

    setup_kernel<<<35, 256, 0, stream>>>(
        (const unsigned*)tmask, Wsrc, Wtrg, Wout, asrc, atrg,
        c_src, c_trg, Wt_t, Wt_o, flag);

    mid_kernel<<<768, 256, 0, stream>>>(
        src, trg, c_src, c_trg, Wt_t, Vt, ssrc, strg, tmask, flag, estg);

    combo_kernel<<<1024, 512, 0, stream>>>(
        ssrc, strg, smask, tmask, flag, Vt, Wt_o, estg, attn, out);
}